// Round 7
// baseline (366.138 us; speedup 1.0000x reference)
//
#include <hip/hip_runtime.h>
#include <math.h>

#define SS 512
#define BB 256
#define DIN 202
#define HH 100
#define TT 19

typedef short short8 __attribute__((ext_vector_type(8)));
typedef float f32x4 __attribute__((ext_vector_type(4)));

__device__ __forceinline__ float rl(float v, int i) {
    return __int_as_float(__builtin_amdgcn_readlane(__float_as_int(v), i));
}
__device__ __forceinline__ float rfl(float v) {
    return __int_as_float(__builtin_amdgcn_readfirstlane(__float_as_int(v)));
}
__device__ __forceinline__ unsigned short f2bf(float f) {
  unsigned u = __float_as_uint(f);
  u += 0x7fff + ((u >> 16) & 1);   // RNE
  return (unsigned short)(u >> 16);
}
__device__ __forceinline__ float bf2f(unsigned v) {
  return __int_as_float((int)(v << 16));
}
__device__ __forceinline__ float fast_tanh(float z) {
  float e = __expf(2.f * z);
  return (e - 1.f) * __fdividef(1.f, e + 1.f);
}
__device__ __forceinline__ void gl_lds16(const void* g, void* l) {
  __builtin_amdgcn_global_load_lds(
      (const __attribute__((address_space(1))) unsigned int*)g,
      (__attribute__((address_space(3))) unsigned int*)l, 16, 0, 0);
}

// ---------------------------------------------------------------------------
// K0: pack W = [Wf;Wb] (200x202 fp32) into frag-linear bf16 tiles.
// Also zeroes d_out (replaces the memset dispatch).
// ---------------------------------------------------------------------------
__global__ __launch_bounds__(256) void k_cvtW(
    const float* __restrict__ Wf, const float* __restrict__ Wb,
    unsigned short* __restrict__ Wfrag, float* __restrict__ outp) {
  if (blockIdx.x == 0 && threadIdx.x == 0) *outp = 0.f;
  int w = blockIdx.x * 256 + threadIdx.x;
  if (w >= 7 * 13 * 64) return;
  int kc = w / (13 * 64);
  int r = w % (13 * 64);
  int ft = r >> 6, l = r & 63;
  int nn = ft * 16 + (l & 15);
  int kb = kc * 32 + (l >> 4) * 8;
  union { unsigned short s[8]; int4 v; } pk;
  #pragma unroll
  for (int e = 0; e < 8; ++e) {
    int k = kb + e;
    float vv = 0.f;
    if (k < DIN) {
      if (nn < 100) vv = Wf[(size_t)nn * DIN + k];
      else if (nn < 200) vv = Wb[(size_t)(nn - 100) * DIN + k];
    }
    pk.s[e] = f2bf(vv);
  }
  *(int4*)&Wfrag[(size_t)w * 8] = pk.v;
}

// ---------------------------------------------------------------------------
// K1: input projection (bf16 MFMA), unchanged from R6 (passed).
// ---------------------------------------------------------------------------
__global__ __launch_bounds__(256) void k_inproj(
    const float* __restrict__ x, const unsigned short* __restrict__ Wfrag,
    const float* __restrict__ bihf, const float* __restrict__ bhhf,
    const float* __restrict__ bihb, const float* __restrict__ bhhb,
    unsigned short* __restrict__ xpT0, unsigned short* __restrict__ xpT1) {
  __shared__ __align__(16) char smem_raw[28672];
  __shared__ float lbias[208];
  short* lA = (short*)smem_raw;
  short* lB = (short*)(smem_raw + 8192);
  const int t = threadIdx.x;
  const int m0 = blockIdx.x * 128;
  const int s_idx = m0 >> 8;
  const int bhalf = (m0 >> 7) & 1;
  const int wv = t >> 6, lane = t & 63;
  const int li = lane & 15;

  if (t < 208) {
    float bv = 0.f;
    if (t < 100) bv = bihf[t] + bhhf[t];
    else if (t < 200) bv = bihb[t - 100] + bhhb[t - 100];
    lbias[t] = bv;
  }

  f32x4 acc[2][13];
  #pragma unroll
  for (int mf = 0; mf < 2; ++mf)
    #pragma unroll
    for (int nf = 0; nf < 13; ++nf)
      acc[mf][nf] = (f32x4){0.f, 0.f, 0.f, 0.f};

  for (int kc = 0; kc < 7; ++kc) {
    const int k0 = kc * 32;
    __syncthreads();
    #pragma unroll
    for (int r = 0; r < 2; ++r) {
      int u = t + 256 * r;
      int ft = u >> 6, ul = u & 63;
      int i = ul & 15, kq = ul >> 4;
      int kbase = k0 + kq * 8;
      const float* src = x + (size_t)(m0 + ft * 16 + i) * DIN + kbase;
      union { unsigned short s[8]; int4 v; } pk;
      if (kbase + 7 < DIN) {
        float2 v0 = *(const float2*)(src);
        float2 v1 = *(const float2*)(src + 2);
        float2 v2 = *(const float2*)(src + 4);
        float2 v3 = *(const float2*)(src + 6);
        pk.s[0] = f2bf(v0.x); pk.s[1] = f2bf(v0.y);
        pk.s[2] = f2bf(v1.x); pk.s[3] = f2bf(v1.y);
        pk.s[4] = f2bf(v2.x); pk.s[5] = f2bf(v2.y);
        pk.s[6] = f2bf(v3.x); pk.s[7] = f2bf(v3.y);
      } else {
        #pragma unroll
        for (int e = 0; e < 8; ++e)
          pk.s[e] = (kbase + e < DIN) ? f2bf(src[e]) : 0;
      }
      *(int4*)&lA[ft * 512 + ul * 8] = pk.v;
    }
    #pragma unroll
    for (int i = 0; i < 4; ++i) {
      int j = i * 4 + wv;
      if (j < 13)
        gl_lds16(Wfrag + ((size_t)(kc * 13 + j)) * 512, &lB[j * 512]);
    }
    __syncthreads();
    short8 a0 = *(const short8*)&lA[(2 * wv + 0) * 512 + lane * 8];
    short8 a1 = *(const short8*)&lA[(2 * wv + 1) * 512 + lane * 8];
    #pragma unroll
    for (int nf = 0; nf < 13; ++nf) {
      short8 b = *(const short8*)&lB[nf * 512 + lane * 8];
      acc[0][nf] = __builtin_amdgcn_mfma_f32_16x16x32_bf16(a0, b, acc[0][nf], 0, 0, 0);
      acc[1][nf] = __builtin_amdgcn_mfma_f32_16x16x32_bf16(a1, b, acc[1][nf], 0, 0, 0);
    }
  }
  __syncthreads();
  unsigned short* ep = (unsigned short*)smem_raw;
  float biasv[13];
  #pragma unroll
  for (int nf = 0; nf < 13; ++nf) biasv[nf] = lbias[nf * 16 + li];
  const int r0 = (lane >> 4) * 4;
  #pragma unroll
  for (int d = 0; d < 2; ++d) {
    if (d == 1) __syncthreads();
    #pragma unroll
    for (int mf = 0; mf < 2; ++mf) {
      int lrb = (2 * wv + mf) * 16 + r0;
      #pragma unroll
      for (int nf = 0; nf < 13; ++nf) {
        int col = nf * 16 + li;
        int c = col - 100 * d;
        if (c >= 0 && c < 100) {
          #pragma unroll
          for (int r = 0; r < 4; ++r)
            ep[(lrb + r) * 112 + c] = f2bf(acc[mf][nf][r] + biasv[nf]);
        }
      }
    }
    __syncthreads();
    unsigned short* dst0 = d ? xpT1 : xpT0;
    #pragma unroll
    for (int it = 0; it < 7; ++it) {
      int u = t + 256 * it;
      if (u < 1664) {
        int bgrpL = u / 208;
        int rem = u - bgrpL * 208;
        int u8 = rem >> 4, nn = rem & 15;
        int lr = bgrpL * 16 + nn;
        int4 v = *(const int4*)&ep[lr * 112 + u8 * 8];
        size_t off = ((((size_t)s_idx * 16 + bhalf * 8 + bgrpL) * 13 + u8) * 16 + nn) * 8;
        *(int4*)(dst0 + off) = v;
      }
    }
  }
}

// ---------------------------------------------------------------------------
// K2 v7: all-LDS MFMA RNN scan, 16 segments x 32-step warmup.
// Grid 512 (2 blocks/CU for stall overlap): dir=bid&1, bgrp=(bid>>1)&15,
// seg=bid>>5 (0..15). Segment outputs [32seg, 32seg+32), warmup 32 (seg>0).
// ---------------------------------------------------------------------------
__global__ __launch_bounds__(320) void k_rnn(
    const unsigned short* __restrict__ xpT0, const unsigned short* __restrict__ xpT1,
    const float* __restrict__ Whf, const float* __restrict__ Whb,
    const float* __restrict__ Wtag, float* __restrict__ plogF, float* __restrict__ plogB) {
  const int bid = blockIdx.x;
  const int dir = bid & 1;
  const int bgrp = (bid >> 1) & 15;
  const int b0 = bgrp * 16;
  const int seg = bid >> 5;
  const int outbase = 32 * seg;
  const int start = (seg == 0) ? 0 : (outbase - 32);
  const int nch = (outbase + 32 - start) >> 3;   // 4 or 8

  const float* Whh = dir ? Whb : Whf;
  const unsigned short* xpX = dir ? xpT1 : xpT0;
  float* plog = dir ? plogB : plogF;

  __shared__ short ringc[9][3][512];
  __shared__ short ring3[9][128];
  __shared__ unsigned short xpl[13312];
  __shared__ unsigned short larc[8 * 16 * 20];
  __shared__ short dummy16[8];

  const int t = threadIdx.x;
  const int wv = t >> 6, lane = t & 63;
  const int n = lane & 15, q = lane >> 4;

  for (int i = t; i < 3 * 512; i += 320) ringc[0][i >> 9][i & 511] = 0;
  for (int i = t; i < 9 * 128; i += 320) ring3[i >> 7][i & 127] = 0;
  if (t < 8) dummy16[t] = 0;

  // ---- one-time A-fragment load ----
  short8 afA[4], afB[4];
  #pragma unroll
  for (int q2 = 0; q2 < 4; ++q2) { afA[q2] = (short8){0,0,0,0,0,0,0,0}; afB[q2] = (short8){0,0,0,0,0,0,0,0}; }
  {
    const float* baseA = nullptr; const float* baseB = nullptr;
    if (wv < 3) {
      int rA = 32 * wv + n, rB = 32 * wv + 16 + n;
      if (rA < HH) baseA = Whh + (size_t)rA * HH;
      if (rB < HH) baseB = Whh + (size_t)rB * HH;
    } else if (wv == 3) {
      int rA = 96 + n;
      if (rA < HH) baseA = Whh + (size_t)rA * HH;
    } else {
      int tA = n, tB = 16 + n;
      if (tA < TT) baseA = Wtag + (size_t)tA * (2 * HH) + dir * HH;
      if (tB < TT) baseB = Wtag + (size_t)tB * (2 * HH) + dir * HH;
    }
    #pragma unroll
    for (int q2 = 0; q2 < 4; ++q2) {
      union { unsigned short s[8]; short8 v; } pa, pb;
      #pragma unroll
      for (int e = 0; e < 8; ++e) {
        int k = 32 * q2 + 8 * q + e;
        pa.s[e] = (baseA && k < HH) ? f2bf(baseA[k]) : 0;
        pb.s[e] = (baseB && k < HH) ? f2bf(baseB[k]) : 0;
      }
      afA[q2] = pa.v; afB[q2] = pb.v;
    }
  }

  int slj[6], remj[6];
  #pragma unroll
  for (int i = 0; i < 6; ++i) {
    int j = i * 5 + wv;
    int unit = j * 64 + lane;
    slj[i] = unit / 208;
    remj[i] = unit - slj[i] * 208;
  }

  const int fA = (wv < 3) ? 2 * wv : 6;
  const int offA = ((2 * fA + (q >> 1)) * 16 + n) * 16 + (q & 1) * 8;
  const int offB = ((2 * (2 * wv + 1) + (q >> 1)) * 16 + n) * 16 + (q & 1) * 8;

  for (int cc = 0; cc < nch; ++cc) {
    // ================= mega phase =================
    if (cc > 0) {
      int baseh = start + (cc - 1) * 8 - 1;
      if (t < 128) {
        int sl = t >> 4, nn2 = t & 15;
        int hs = baseh + sl;
        if (hs >= outbase) {
          int pos = dir ? (511 - hs) : hs;
          float* dst = plog + ((size_t)pos * 256 + b0 + nn2) * 20;
          const unsigned short* src = &larc[(sl * 16 + nn2) * 20];
          #pragma unroll
          for (int j5 = 0; j5 < 5; ++j5) {
            uint2 rv = *(const uint2*)&src[j5 * 4];
            float4 o;
            o.x = bf2f(rv.x & 0xffffu); o.y = bf2f(rv.x >> 16);
            o.z = bf2f(rv.y & 0xffffu); o.w = bf2f(rv.y >> 16);
            *(float4*)&dst[j5 * 4] = o;
          }
        }
      }
      if (t < 192) {
        *(int4*)&ringc[0][t >> 6][(t & 63) * 8] = *(const int4*)&ringc[8][t >> 6][(t & 63) * 8];
      } else if (t < 208) {
        int i = t - 192;
        *(int4*)&ring3[0][i * 8] = *(const int4*)&ring3[8][i * 8];
      }
    }
    #pragma unroll
    for (int i = 0; i < 6; ++i) {
      int j = i * 5 + wv;
      if (j < 26) {
        int s = start + cc * 8 + slj[i];
        int sq = dir ? (511 - s) : s;
        gl_lds16(xpX + (((size_t)sq * 16 + bgrp) * 208 + remj[i]) * 8, &xpl[j * 512]);
      }
    }
    __syncthreads();

    // ================= 8 inner steps (LDS only) =================
    #pragma unroll
    for (int sl = 0; sl < 8; ++sl) {
      short8 hc0 = *(const short8*)&ringc[sl][0][lane * 8];
      short8 hc1 = *(const short8*)&ringc[sl][1][lane * 8];
      short8 hc2 = *(const short8*)&ringc[sl][2][lane * 8];
      short8 hc3 = *(const short8*)((q == 0) ? &ring3[sl][n * 8] : &dummy16[0]);
      f32x4 z4 = {0.f, 0.f, 0.f, 0.f};
      if (wv < 4) {
        int xb = sl * 3328;
        int oA = xb + offA; if (oA > 26616) oA = 26616;
        uint2 sa = *(const uint2*)((const char*)xpl + oA);
        f32x4 seedA = {bf2f(sa.x & 0xffffu), bf2f(sa.x >> 16),
                       bf2f(sa.y & 0xffffu), bf2f(sa.y >> 16)};
        f32x4 aA  = __builtin_amdgcn_mfma_f32_16x16x32_bf16(afA[0], hc0, seedA, 0, 0, 0);
        f32x4 aA2 = __builtin_amdgcn_mfma_f32_16x16x32_bf16(afA[1], hc1, z4, 0, 0, 0);
        aA  = __builtin_amdgcn_mfma_f32_16x16x32_bf16(afA[2], hc2, aA, 0, 0, 0);
        aA2 = __builtin_amdgcn_mfma_f32_16x16x32_bf16(afA[3], hc3, aA2, 0, 0, 0);
        aA += aA2;
        uint2 valA;
        {
          float h0 = fast_tanh(aA[0]), h1 = fast_tanh(aA[1]);
          float h2 = fast_tanh(aA[2]), h3 = fast_tanh(aA[3]);
          valA.x = ((unsigned)f2bf(h1) << 16) | f2bf(h0);
          valA.y = ((unsigned)f2bf(h3) << 16) | f2bf(h2);
        }
        if (wv < 3) {
          int oB = xb + offB;
          uint2 sb = *(const uint2*)((const char*)xpl + oB);
          f32x4 seedB = {bf2f(sb.x & 0xffffu), bf2f(sb.x >> 16),
                         bf2f(sb.y & 0xffffu), bf2f(sb.y >> 16)};
          f32x4 aB  = __builtin_amdgcn_mfma_f32_16x16x32_bf16(afB[0], hc0, seedB, 0, 0, 0);
          f32x4 aB2 = __builtin_amdgcn_mfma_f32_16x16x32_bf16(afB[1], hc1, z4, 0, 0, 0);
          aB  = __builtin_amdgcn_mfma_f32_16x16x32_bf16(afB[2], hc2, aB, 0, 0, 0);
          aB2 = __builtin_amdgcn_mfma_f32_16x16x32_bf16(afB[3], hc3, aB2, 0, 0, 0);
          aB += aB2;
          uint2 valB;
          {
            float h0 = fast_tanh(aB[0]), h1 = fast_tanh(aB[1]);
            float h2 = fast_tanh(aB[2]), h3 = fast_tanh(aB[3]);
            valB.x = ((unsigned)f2bf(h1) << 16) | f2bf(h0);
            valB.y = ((unsigned)f2bf(h3) << 16) | f2bf(h2);
          }
          *(uint2*)&ringc[sl + 1][wv][(((q >> 1)) * 16 + n) * 8 + 4 * (q & 1)] = valA;
          *(uint2*)&ringc[sl + 1][wv][((2 + (q >> 1)) * 16 + n) * 8 + 4 * (q & 1)] = valB;
        } else {
          if (q == 0) *(uint2*)&ring3[sl + 1][n * 8] = valA;
        }
      } else {
        f32x4 aA  = __builtin_amdgcn_mfma_f32_16x16x32_bf16(afA[0], hc0, z4, 0, 0, 0);
        f32x4 aA2 = __builtin_amdgcn_mfma_f32_16x16x32_bf16(afA[1], hc1, z4, 0, 0, 0);
        aA  = __builtin_amdgcn_mfma_f32_16x16x32_bf16(afA[2], hc2, aA, 0, 0, 0);
        aA2 = __builtin_amdgcn_mfma_f32_16x16x32_bf16(afA[3], hc3, aA2, 0, 0, 0);
        aA += aA2;
        f32x4 aB  = __builtin_amdgcn_mfma_f32_16x16x32_bf16(afB[0], hc0, z4, 0, 0, 0);
        f32x4 aB2 = __builtin_amdgcn_mfma_f32_16x16x32_bf16(afB[1], hc1, z4, 0, 0, 0);
        aB  = __builtin_amdgcn_mfma_f32_16x16x32_bf16(afB[2], hc2, aB, 0, 0, 0);
        aB2 = __builtin_amdgcn_mfma_f32_16x16x32_bf16(afB[3], hc3, aB2, 0, 0, 0);
        aB += aB2;
        uint2 vA, vB;
        vA.x = ((unsigned)f2bf(aA[1]) << 16) | f2bf(aA[0]);
        vA.y = ((unsigned)f2bf(aA[3]) << 16) | f2bf(aA[2]);
        vB.x = ((unsigned)f2bf(aB[1]) << 16) | f2bf(aB[0]);
        vB.y = ((unsigned)f2bf(aB[3]) << 16) | f2bf(aB[2]);
        *(uint2*)&larc[(sl * 16 + n) * 20 + 4 * q] = vA;
        if (q == 0) *(uint2*)&larc[(sl * 16 + n) * 20 + 16] = vB;
      }
      __syncthreads();
    }
  }
  // final flush of last chunk's archive
  {
    int baseh = start + (nch - 1) * 8 - 1;
    if (t < 128) {
      int sl = t >> 4, nn2 = t & 15;
      int hs = baseh + sl;
      if (hs >= outbase) {
        int pos = dir ? (511 - hs) : hs;
        float* dst = plog + ((size_t)pos * 256 + b0 + nn2) * 20;
        const unsigned short* src = &larc[(sl * 16 + nn2) * 20];
        #pragma unroll
        for (int j5 = 0; j5 < 5; ++j5) {
          uint2 rv = *(const uint2*)&src[j5 * 4];
          float4 o;
          o.x = bf2f(rv.x & 0xffffu); o.y = bf2f(rv.x >> 16);
          o.z = bf2f(rv.y & 0xffffu); o.w = bf2f(rv.y >> 16);
          *(float4*)&dst[j5 * 4] = o;
        }
      }
    }
  }
  // logits for the segment's final h (ring slot 8)
  if (wv == 4) {
    short8 hc0 = *(const short8*)&ringc[8][0][lane * 8];
    short8 hc1 = *(const short8*)&ringc[8][1][lane * 8];
    short8 hc2 = *(const short8*)&ringc[8][2][lane * 8];
    short8 hc3 = *(const short8*)((q == 0) ? &ring3[8][n * 8] : &dummy16[0]);
    f32x4 z4 = {0.f, 0.f, 0.f, 0.f};
    f32x4 aA  = __builtin_amdgcn_mfma_f32_16x16x32_bf16(afA[0], hc0, z4, 0, 0, 0);
    f32x4 aA2 = __builtin_amdgcn_mfma_f32_16x16x32_bf16(afA[1], hc1, z4, 0, 0, 0);
    aA  = __builtin_amdgcn_mfma_f32_16x16x32_bf16(afA[2], hc2, aA, 0, 0, 0);
    aA2 = __builtin_amdgcn_mfma_f32_16x16x32_bf16(afA[3], hc3, aA2, 0, 0, 0);
    aA += aA2;
    f32x4 aB  = __builtin_amdgcn_mfma_f32_16x16x32_bf16(afB[0], hc0, z4, 0, 0, 0);
    f32x4 aB2 = __builtin_amdgcn_mfma_f32_16x16x32_bf16(afB[1], hc1, z4, 0, 0, 0);
    aB  = __builtin_amdgcn_mfma_f32_16x16x32_bf16(afB[2], hc2, aB, 0, 0, 0);
    aB2 = __builtin_amdgcn_mfma_f32_16x16x32_bf16(afB[3], hc3, aB2, 0, 0, 0);
    aB += aB2;
    int hs = start + nch * 8 - 1;
    int pos = dir ? (511 - hs) : hs;
    float* dst = plog + ((size_t)pos * 256 + b0 + n) * 20;
    #pragma unroll
    for (int r = 0; r < 4; ++r) dst[4 * q + r] = aA[r];
    if (q == 0) {
      #pragma unroll
      for (int r = 0; r < 4; ++r) dst[16 + r] = aB[r];
    }
  }
}

// ---------------------------------------------------------------------------
// K4 (fused softmax+CRF) v7: 2 waves/block, grid 256 (2 sequences/CU), and
// register prefetch of next chunk's logits before the serial 64-step loop.
// ---------------------------------------------------------------------------
__global__ __launch_bounds__(128) void k_crf(
    const float* __restrict__ plogF, const float* __restrict__ plogB,
    const float* __restrict__ btag, const int* __restrict__ y,
    const float* __restrict__ start, const float* __restrict__ endt,
    const float* __restrict__ trans, float* __restrict__ out) {
  __shared__ float ltr[TT * TT];
  __shared__ float ltb[20];
  __shared__ float lem[2][64 * 21];
  const int t = threadIdx.x;
  const int wave = t >> 6, lane = t & 63;
  const int n = blockIdx.x * 2 + wave;
  for (int i = t; i < TT * TT; i += 128) ltr[i] = trans[i];
  if (t < 20) ltb[t] = (t < TT) ? btag[t] : 0.f;
  __syncthreads();
  const int* yn = y + n * BB;
  float Ereg[TT];
  #pragma unroll
  for (int i = 0; i < TT; ++i) Ereg[i] = (lane < TT) ? __expf(ltr[i * TT + lane]) : 0.f;

  const size_t nbase = (size_t)n * BB * 20;
  float fpf[20], fpb[20];
  #pragma unroll
  for (int i = 0; i < 20; ++i) {
    fpf[i] = plogF[nbase + lane + 64 * i];
    fpb[i] = plogB[nbase + lane + 64 * i];
  }

  float num = 0.f;
  float alpha = -1e30f;
  for (int c = 0; c < 4; ++c) {
    // commit prefetched chunk to LDS (stride-21)
    #pragma unroll
    for (int i = 0; i < 20; ++i) {
      int u = lane + 64 * i;
      int row = u / 20, col = u - row * 20;
      lem[wave][row * 21 + col] = fpf[i] + fpb[i] + ltb[col];
    }
    // prefetch next chunk (latency hidden under the serial loop below)
    if (c < 3) {
      const size_t gb = nbase + (size_t)(c + 1) * 1280;
      #pragma unroll
      for (int i = 0; i < 20; ++i) {
        fpf[i] = plogF[gb + lane + 64 * i];
        fpb[i] = plogB[gb + lane + 64 * i];
      }
    }
    // softmax: lane l owns row l
    {
      float vv[TT];
      float mx = -1e30f;
      #pragma unroll
      for (int j = 0; j < TT; ++j) { vv[j] = lem[wave][lane * 21 + j]; mx = fmaxf(mx, vv[j]); }
      float ssum = 0.f;
      #pragma unroll
      for (int j = 0; j < TT; ++j) { vv[j] = __expf(vv[j] - mx); ssum += vv[j]; }
      float inv = __fdividef(1.f, ssum);
      #pragma unroll
      for (int j = 0; j < TT; ++j) lem[wave][lane * 21 + j] = vv[j] * inv;
    }
    {  // numerator piece: l = c*64 + lane
      int l = c * 64 + lane;
      int yt = yn[l];
      num += lem[wave][lane * 21 + yt];
      if (l < BB - 1) num += ltr[yt * TT + yn[l + 1]];
    }
    int llstart = 0;
    if (c == 0) {
      alpha = (lane < TT) ? (start[lane] + lem[wave][lane]) : -1e30f;
      llstart = 1;
    }
    for (int ll = llstart; ll < 64; ++ll) {
      float m = rfl(alpha);
      float ea = __expf(alpha - m);
      float s0 = 0.f, s1 = 0.f;
      #pragma unroll
      for (int i = 0; i < TT; i += 2) {
        s0 = fmaf(rl(ea, i), Ereg[i], s0);
        if (i + 1 < TT) s1 = fmaf(rl(ea, i + 1), Ereg[i + 1], s1);
      }
      float ssum = s0 + s1;
      float em_l = (lane < TT) ? lem[wave][ll * 21 + lane] : 0.f;
      alpha = em_l + m + __logf(ssum);
    }
  }
  #pragma unroll
  for (int o = 1; o < 64; o <<= 1) num += __shfl_xor(num, o);
  float av = alpha + ((lane < TT) ? endt[lane] : 0.f);
  float m2 = rfl(av);
  float ex = (lane < TT) ? __expf(av - m2) : 0.f;
  #pragma unroll
  for (int o = 1; o < 64; o <<= 1) ex += __shfl_xor(ex, o);
  if (lane == 0) {
    float denom = m2 + __logf(ex);
    float res = (start[yn[0]] + endt[yn[BB - 1]] + num) - denom;
    atomicAdd(out, res);
  }
}

// ---------------------------------------------------------------------------
extern "C" void kernel_launch(void* const* d_in, const int* in_sizes, int n_in,
                              void* d_out, int out_size, void* d_ws, size_t ws_size,
                              hipStream_t stream) {
  const float* x     = (const float*)d_in[0];
  const int*   y     = (const int*)d_in[1];
  const float* Wihf  = (const float*)d_in[2];
  const float* Whhf  = (const float*)d_in[3];
  const float* bihf  = (const float*)d_in[4];
  const float* bhhf  = (const float*)d_in[5];
  const float* Wihb  = (const float*)d_in[6];
  const float* Whhb  = (const float*)d_in[7];
  const float* bihb  = (const float*)d_in[8];
  const float* bihb2 = (const float*)d_in[9];
  const float* Wtag  = (const float*)d_in[10];
  const float* btag  = (const float*)d_in[11];
  const float* stt   = (const float*)d_in[12];
  const float* endt  = (const float*)d_in[13];
  const float* trans = (const float*)d_in[14];

  char* w = (char*)d_ws;
  unsigned short* Wfrag = (unsigned short*)w;  w += 128 * 1024;
  unsigned short* xpT0  = (unsigned short*)w;  w += (size_t)512 * 16 * 208 * 16;
  unsigned short* xpT1  = (unsigned short*)w;  w += (size_t)512 * 16 * 208 * 16;
  float* plogF = (float*)w;  w += (size_t)131072 * 20 * 4;
  float* plogB = (float*)w;  w += (size_t)131072 * 20 * 4;

  k_cvtW<<<23, 256, 0, stream>>>(Wihf, Wihb, Wfrag, (float*)d_out);
  k_inproj<<<1024, 256, 0, stream>>>(x, Wfrag, bihf, bhhf, bihb, bihb2, xpT0, xpT1);
  k_rnn<<<512, 320, 0, stream>>>(xpT0, xpT1, Whhf, Whhb, Wtag, plogF, plogB);
  k_crf<<<256, 128, 0, stream>>>(plogF, plogB, btag, y, stt, endt, trans, (float*)d_out);
}